// Round 7
// baseline (155.603 us; speedup 1.0000x reference)
//
#include <hip/hip_runtime.h>
#include <math.h>

// Problem constants
#define NPIX   131072      // 32 * 64 * 64 pixels
#define KCODES 512
#define DDIM   64
#define HWSZ   4096        // 64*64
#define NELEM  8388608     // NPIX * DDIM

// d_out layout (fp32): [0]=loss, [1..1+NELEM)=q_nchw, [1+NELEM]=perplexity,
// [2+NELEM .. 2+2*NELEM)=q_nhwc flat
#define OUT_NCHW_OFF 1
#define OUT_PERP_IDX (1 + NELEM)
#define OUT_NHWC_OFF (2 + NELEM)

// ws layout (fp32 words): [0]=loss, [16..528)=|e|^2, [544..1056)=counts(uint),
// [1056]=ticket, [2048..) = e bf16 hi/lo fragments in MFMA B-layout (128KB)
#define WS_NRM_OFF  16
#define WS_CNT_OFF  544
#define WS_TICKET   1056
#define WS_FRAG_F32 2048

#define NBLOCKS (NPIX / 256)   // 512 blocks, 256 pixels each (R0 geometry)

typedef __bf16 bf16x8 __attribute__((ext_vector_type(8)));
typedef float  f32x4  __attribute__((ext_vector_type(4)));

// Fused prep (memset + norms + pack in one dispatch; proven R2-R6). Thread
// tid = [ctile(32)][kstep(2)][h(2)][lane(64)] packs e into bf16 hi/lo MFMA
// B-fragments (16x16x32: B[k][n], n=lane&15, k=(lane>>4)*8+j); 16B coalesced.
// tid<512 computes |e|^2; tid in [512,1024) zeros counts; tid 0 zeros loss;
// tid 1024 zeros the last-block ticket.
__global__ __launch_bounds__(256) void vq_prep(const float* __restrict__ emb,
                                               float* __restrict__ ws) {
    int tid  = blockIdx.x * 256 + threadIdx.x;   // 0..8191
    if (tid == 0) ws[0] = 0.f;
    if (tid == 2 * KCODES) reinterpret_cast<unsigned*>(ws)[WS_TICKET] = 0u;
    if (tid < KCODES) {
        const float4* e4 = reinterpret_cast<const float4*>(emb + tid * DDIM);
        float s = 0.f;
#pragma unroll
        for (int i = 0; i < 16; ++i) {
            float4 v = e4[i];
            s = fmaf(v.x, v.x, s); s = fmaf(v.y, v.y, s);
            s = fmaf(v.z, v.z, s); s = fmaf(v.w, v.w, s);
        }
        ws[WS_NRM_OFF + tid] = s;
    } else if (tid < 2 * KCODES) {
        reinterpret_cast<unsigned*>(ws)[WS_CNT_OFF + (tid - KCODES)] = 0u;
    }

    int lane = tid & 63;
    int h    = (tid >> 6) & 1;
    int ks   = (tid >> 7) & 1;
    int ct   = tid >> 8;                         // 0..31
    int code = ct * 16 + (lane & 15);
    int d0   = ks * 32 + ((lane >> 4) & 3) * 8;
    const float* src = emb + code * DDIM + d0;
    unsigned short us[8];
#pragma unroll
    for (int j = 0; j < 8; ++j) {
        float f = src[j];
        __bf16 hb = (__bf16)f;                       // RTN
        if (h == 0) {
            us[j] = __builtin_bit_cast(unsigned short, hb);
        } else {
            __bf16 lb = (__bf16)(f - (float)hb);
            us[j] = __builtin_bit_cast(unsigned short, lb);
        }
    }
    uint4 v;
    v.x = us[0] | ((unsigned)us[1] << 16);
    v.y = us[2] | ((unsigned)us[3] << 16);
    v.z = us[4] | ((unsigned)us[5] << 16);
    v.w = us[6] | ((unsigned)us[7] << 16);
    reinterpret_cast<uint4*>(ws + WS_FRAG_F32)[tid] = v;
}

// Main — R0's proven 56.6us structure, INCLUDING its tail ordering. R6 lesson
// (counter-proven): adding __syncthreads right after the global count atomics
// cost ~15us — MFMA busy-time stayed 13.0us while duration rose 56.6->71,
// i.e. pure added stall: all 512 blocks arrive phase-aligned, hammer 16 cache
// lines with 262K serialized L2 atomics, and the barrier's vmcnt(0) makes
// every wave wait with zero overlap. R0's ordering (issue atomics BEFORE the
// epilogue; they drain at the first epilogue barrier, overlapped with the
// gather phase and de-phased across blocks) is restored token-for-token.
// The ticket + fused finale now sit AFTER the epilogue, where all atomics
// have long completed; added cost = two end barriers + ~0.3us on one block.
__global__ __launch_bounds__(256, 2) void vq_main(const float* __restrict__ in,
                                                  const float* __restrict__ emb,
                                                  float* __restrict__ out,
                                                  float* __restrict__ ws) {
    __shared__ __align__(16) float xs[256 * 68];  // x [pix][d] pad-68; reused as q tile
    __shared__ float    x2_lds[256];
    __shared__ float    nrm_lds[KCODES];
    __shared__ int      idx_lds[256];
    __shared__ unsigned cnt_lds[KCODES];
    __shared__ float    red_tot;
    __shared__ int      is_last;
    __shared__ double   rd[4];

    const int t = threadIdx.x;
    cnt_lds[t] = 0u; cnt_lds[t + 256] = 0u;
    if (t == 0) red_tot = 0.f;

    const int pix0 = blockIdx.x << 8;
    const int b    = pix0 >> 12;
    const int hwb  = pix0 & (HWSZ - 1);

    // Stage x (thread t = pixel t): coalesced global reads, b128 LDS writes.
    const float* inb = in + b * (DDIM * HWSZ) + hwb + t;
    float x2 = 0.f;
#pragma unroll
    for (int c = 0; c < DDIM; c += 4) {
        float4 v;
        v.x = inb[(c + 0) * HWSZ]; v.y = inb[(c + 1) * HWSZ];
        v.z = inb[(c + 2) * HWSZ]; v.w = inb[(c + 3) * HWSZ];
        *reinterpret_cast<float4*>(&xs[t * 68 + c]) = v;
        x2 = fmaf(v.x, v.x, x2); x2 = fmaf(v.y, v.y, x2);
        x2 = fmaf(v.z, v.z, x2); x2 = fmaf(v.w, v.w, x2);
    }
    x2_lds[t] = x2;
    nrm_lds[t]       = ws[WS_NRM_OFF + t];
    nrm_lds[t + 256] = ws[WS_NRM_OFF + t + 256];
    __syncthreads();

    const int l = t & 63, wid = t >> 6;   // wave handles pixels [wid*64, +64)

    // A-fragments (A[m][k]: m=lane&15, k=(lane>>4)*8+j), hi/lo bf16 split.
    bf16x8 a_hi[4][2], a_lo[4][2];
#pragma unroll
    for (int pt = 0; pt < 4; ++pt)
#pragma unroll
    for (int ks = 0; ks < 2; ++ks) {
        int pixl = wid * 64 + pt * 16 + (l & 15);
        int d0   = ks * 32 + ((l >> 4) & 3) * 8;
        const float4* p = reinterpret_cast<const float4*>(&xs[pixl * 68 + d0]);
        float4 f0 = p[0], f1 = p[1];
        float fv[8] = {f0.x, f0.y, f0.z, f0.w, f1.x, f1.y, f1.z, f1.w};
        bf16x8 h8, l8;
#pragma unroll
        for (int j = 0; j < 8; ++j) {
            __bf16 hb = (__bf16)fv[j];
            h8[j] = hb;
            l8[j] = (__bf16)(fv[j] - (float)hb);
        }
        a_hi[pt][ks] = h8; a_lo[pt][ks] = l8;
    }

    const uint4* fragp = reinterpret_cast<const uint4*>(ws + WS_FRAG_F32);
    float best[4][4]; int bidx[4][4];
#pragma unroll
    for (int pt = 0; pt < 4; ++pt)
#pragma unroll
    for (int r = 0; r < 4; ++r) { best[pt][r] = 3.4e38f; bidx[pt][r] = 0; }

    // B-frag double buffer: 8 frags/chunk = [ct][ks][h]
    uint4 bcur[8], bnxt[8];
#pragma unroll
    for (int i = 0; i < 8; ++i) {
        int ct = i >> 2, ks = (i >> 1) & 1, h = i & 1;
        bcur[i] = fragp[(((ct) * 2 + ks) * 2 + h) * 64 + l];
    }

    for (int cb = 0; cb < KCODES; cb += 32) {
        int ctb = cb >> 4;
        if (cb + 32 < KCODES) {
#pragma unroll
            for (int i = 0; i < 8; ++i) {
                int ct = i >> 2, ks = (i >> 1) & 1, h = i & 1;
                bnxt[i] = fragp[(((ctb + 2 + ct) * 2 + ks) * 2 + h) * 64 + l];
            }
        }
        // 64 pix x 32 codes: 8 C-tiles, 4-term bf16 split accumulated in fp32
        f32x4 acc[4][2];
#pragma unroll
        for (int pt = 0; pt < 4; ++pt)
#pragma unroll
        for (int ct = 0; ct < 2; ++ct) {
            f32x4 a = {0.f, 0.f, 0.f, 0.f};
#pragma unroll
            for (int ks = 0; ks < 2; ++ks) {
                bf16x8 bh = __builtin_bit_cast(bf16x8, bcur[ct * 4 + ks * 2 + 0]);
                bf16x8 bl = __builtin_bit_cast(bf16x8, bcur[ct * 4 + ks * 2 + 1]);
                a = __builtin_amdgcn_mfma_f32_16x16x32_bf16(a_hi[pt][ks], bh, a, 0, 0, 0);
                a = __builtin_amdgcn_mfma_f32_16x16x32_bf16(a_hi[pt][ks], bl, a, 0, 0, 0);
                a = __builtin_amdgcn_mfma_f32_16x16x32_bf16(a_lo[pt][ks], bh, a, 0, 0, 0);
                a = __builtin_amdgcn_mfma_f32_16x16x32_bf16(a_lo[pt][ks], bl, a, 0, 0, 0);
            }
            acc[pt][ct] = a;
        }
        // argmin update; C/D: col(code)=lane&15, row(pix)=(lane>>4)*4+reg
#pragma unroll
        for (int ct = 0; ct < 2; ++ct) {
            int code = cb + ct * 16 + (l & 15);
            float nv = nrm_lds[code];
#pragma unroll
            for (int pt = 0; pt < 4; ++pt)
#pragma unroll
            for (int r = 0; r < 4; ++r) {
                float d = fmaf(-2.f, acc[pt][ct][r], nv);
                if (d < best[pt][r]) { best[pt][r] = d; bidx[pt][r] = code; }
            }
        }
#pragma unroll
        for (int i = 0; i < 8; ++i) bcur[i] = bnxt[i];
    }

    // Cross-lane argmin within each 16-lane group (codes spread over lane&15);
    // (dist, then idx) min = exact first-min semantics.
#pragma unroll
    for (int off = 1; off < 16; off <<= 1) {
#pragma unroll
        for (int pt = 0; pt < 4; ++pt)
#pragma unroll
        for (int r = 0; r < 4; ++r) {
            float ob = __shfl_xor(best[pt][r], off, 64);
            int   oi = __shfl_xor(bidx[pt][r], off, 64);
            bool take = (ob < best[pt][r]) || (ob == best[pt][r] && oi < bidx[pt][r]);
            if (take) { best[pt][r] = ob; bidx[pt][r] = oi; }
        }
    }
    if ((l & 15) == 0) {
        int q = l >> 4;
        float lp = 0.f;
#pragma unroll
        for (int pt = 0; pt < 4; ++pt)
#pragma unroll
        for (int r = 0; r < 4; ++r) {
            int pixl = wid * 64 + pt * 16 + q * 4 + r;
            idx_lds[pixl] = bidx[pt][r];
            atomicAdd(&cnt_lds[bidx[pt][r]], 1u);
            lp += x2_lds[pixl] + best[pt][r];   // |x-e|^2 = x^2 + (|e|^2 - 2x.e)
        }
        atomicAdd(&red_tot, lp);
    }
    __syncthreads();

    // Issue global atomics NOW (R0 ordering): they drain at the first epilogue
    // barrier, overlapped with the gather phase — no dedicated drain barrier.
    if (t == 0) atomicAdd(ws, red_tot);
    unsigned* gcnt = reinterpret_cast<unsigned*>(ws) + WS_CNT_OFF;
    atomicAdd(gcnt + t, cnt_lds[t]);
    atomicAdd(gcnt + t + 256, cnt_lds[t + 256]);

    // Epilogue (R0-proven, token-identical): padded LDS tile (aliases xs)
    // makes both NHWC and NCHW writes coalesced and LDS-conflict-free.
    float* q_lds = xs;                  // [64][65]
    float* out2 = out + OUT_NCHW_OFF;   // NCHW
    float* out3 = out + OUT_NHWC_OFF;   // NHWC flat (float2-aligned)
    const float2* emb2 = reinterpret_cast<const float2*>(emb);
    float2* out3_2 = reinterpret_cast<float2*>(out3);

    for (int s = 0; s < 4; ++s) {
#pragma unroll
        for (int it = 0; it < 8; ++it) {
            int fid = it * 256 + t;
            int pp  = fid >> 5;
            int c2  = fid & 31;
            int row = idx_lds[s * 64 + pp];
            float2 v = emb2[row * 32 + c2];
            out3_2[(size_t)(pix0 + s * 64 + pp) * 32 + c2] = v;
            q_lds[pp * 65 + c2 * 2 + 0] = v.x;
            q_lds[pp * 65 + c2 * 2 + 1] = v.y;
        }
        __syncthreads();
#pragma unroll
        for (int it = 0; it < 16; ++it) {
            int did = it * 256 + t;
            int c   = did >> 6;
            int hwl = did & 63;
            out2[(size_t)(b * DDIM + c) * HWSZ + hwb + s * 64 + hwl] = q_lds[hwl * 65 + c];
        }
        __syncthreads();
    }

    // Ticket + fused finale (proven R3-R6), now after the epilogue: every
    // thread's count atomics were drained at its first epilogue barrier, so
    // the block's counts are globally visible before its ticket increment.
    if (t == 0) {
        unsigned tk = __hip_atomic_fetch_add(
            reinterpret_cast<unsigned*>(ws) + WS_TICKET, 1u,
            __ATOMIC_ACQ_REL, __HIP_MEMORY_SCOPE_AGENT);
        is_last = (tk == NBLOCKS - 1);
    }
    __syncthreads();
    if (is_last) {
        double s = 0.0;
        for (int k = t; k < KCODES; k += 256) {
            unsigned cv = __hip_atomic_load(gcnt + k, __ATOMIC_RELAXED,
                                            __HIP_MEMORY_SCOPE_AGENT);
            double p = (double)cv / (double)NPIX;
            s += p * log(p + 1e-10);
        }
#pragma unroll
        for (int o = 32; o > 0; o >>= 1) s += __shfl_xor(s, o, 64);
        if ((t & 63) == 0) rd[t >> 6] = s;
        __syncthreads();
        if (t == 0) {
            double tot = rd[0] + rd[1] + rd[2] + rd[3];
            out[OUT_PERP_IDX] = (float)exp(-tot);
            float lossv = __hip_atomic_load(ws, __ATOMIC_RELAXED,
                                            __HIP_MEMORY_SCOPE_AGENT);
            out[0] = 0.25f * lossv / (float)NELEM;
        }
    }
}

extern "C" void kernel_launch(void* const* d_in, const int* in_sizes, int n_in,
                              void* d_out, int out_size, void* d_ws, size_t ws_size,
                              hipStream_t stream) {
    const float* in  = (const float*)d_in[0];
    const float* emb = (const float*)d_in[1];
    float* out = (float*)d_out;
    float* ws  = (float*)d_ws;

    // vq_prep zeroes loss+counts+ticket and overwrites norms + frag region.
    vq_prep<<<32, 256, 0, stream>>>(emb, ws);
    vq_main<<<NBLOCKS, 256, 0, stream>>>(in, emb, out, ws);
}

// Round 8
// 131.305 us; speedup vs baseline: 1.1850x; 1.1850x over previous
//
#include <hip/hip_runtime.h>
#include <math.h>

// Problem constants
#define NPIX   131072      // 32 * 64 * 64 pixels
#define KCODES 512
#define DDIM   64
#define HWSZ   4096        // 64*64
#define NELEM  8388608     // NPIX * DDIM

// d_out layout (fp32): [0]=loss, [1..1+NELEM)=q_nchw, [1+NELEM]=perplexity,
// [2+NELEM .. 2+2*NELEM)=q_nhwc flat
#define OUT_NCHW_OFF 1
#define OUT_PERP_IDX (1 + NELEM)
#define OUT_NHWC_OFF (2 + NELEM)

// ws layout (fp32 words): [0]=loss, [16..528)=|e|^2, [544..1056)=counts(uint),
// [2048..) = e bf16 hi/lo fragments in MFMA B-layout (byte 8192, 128KB)
#define WS_NRM_OFF  16
#define WS_CNT_OFF  544
#define WS_FRAG_F32 2048

typedef __bf16 bf16x8 __attribute__((ext_vector_type(8)));
typedef float  f32x4  __attribute__((ext_vector_type(4)));

// Fused prep (memset + norms + pack in one dispatch; proven R2-R7). Thread
// tid = [ctile(32)][kstep(2)][h(2)][lane(64)] packs e into bf16 hi/lo MFMA
// B-fragments (16x16x32: B[k][n], n=lane&15, k=(lane>>4)*8+j); 16B coalesced.
// tid<512 computes |e|^2; tid in [512,1024) zeros counts; tid 0 zeros loss.
__global__ __launch_bounds__(256) void vq_prep(const float* __restrict__ emb,
                                               float* __restrict__ ws) {
    int tid  = blockIdx.x * 256 + threadIdx.x;   // 0..8191
    if (tid == 0) ws[0] = 0.f;
    if (tid < KCODES) {
        const float4* e4 = reinterpret_cast<const float4*>(emb + tid * DDIM);
        float s = 0.f;
#pragma unroll
        for (int i = 0; i < 16; ++i) {
            float4 v = e4[i];
            s = fmaf(v.x, v.x, s); s = fmaf(v.y, v.y, s);
            s = fmaf(v.z, v.z, s); s = fmaf(v.w, v.w, s);
        }
        ws[WS_NRM_OFF + tid] = s;
    } else if (tid < 2 * KCODES) {
        reinterpret_cast<unsigned*>(ws)[WS_CNT_OFF + (tid - KCODES)] = 0u;
    }

    int lane = tid & 63;
    int h    = (tid >> 6) & 1;
    int ks   = (tid >> 7) & 1;
    int ct   = tid >> 8;                         // 0..31
    int code = ct * 16 + (lane & 15);
    int d0   = ks * 32 + ((lane >> 4) & 3) * 8;
    const float* src = emb + code * DDIM + d0;
    unsigned short us[8];
#pragma unroll
    for (int j = 0; j < 8; ++j) {
        float f = src[j];
        __bf16 hb = (__bf16)f;                       // RTN
        if (h == 0) {
            us[j] = __builtin_bit_cast(unsigned short, hb);
        } else {
            __bf16 lb = (__bf16)(f - (float)hb);
            us[j] = __builtin_bit_cast(unsigned short, lb);
        }
    }
    uint4 v;
    v.x = us[0] | ((unsigned)us[1] << 16);
    v.y = us[2] | ((unsigned)us[3] << 16);
    v.z = us[4] | ((unsigned)us[5] << 16);
    v.w = us[6] | ((unsigned)us[7] << 16);
    reinterpret_cast<uint4*>(ws + WS_FRAG_F32)[tid] = v;
}

// Main — R0's proven 56.6us kernel, token-exact, NO tail additions.
// R6/R7 lesson (counter-proven, dose-response): an ACQ_REL agent-scope
// ticket atomic in the tail costs 15-30us — its release semantics imply
// s_waitcnt vmcnt(0) + L2 cache maintenance per block (per-XCD L2s are not
// cross-coherent, so agent release must push past L2). MFMA busy-time was
// 13.0-13.4us in R0/R6/R7 alike: the ticket added pure stall. The only
// ordered-atomic-free way to publish counts/loss is a kernel boundary ->
// keep the separate tiny vq_fin dispatch. Relaxed atomicAdds (counts, loss)
// carry no fence and are proven cheap in R0's ordering: issued before the
// epilogue, drained under the gather phase, de-phased across blocks.
__global__ __launch_bounds__(256, 2) void vq_main(const float* __restrict__ in,
                                                  const float* __restrict__ emb,
                                                  float* __restrict__ out,
                                                  float* __restrict__ ws) {
    __shared__ __align__(16) float xs[256 * 68];  // x [pix][d] pad-68; reused as q tile
    __shared__ float    x2_lds[256];
    __shared__ float    nrm_lds[KCODES];
    __shared__ int      idx_lds[256];
    __shared__ unsigned cnt_lds[KCODES];
    __shared__ float    red_tot;

    const int t = threadIdx.x;
    cnt_lds[t] = 0u; cnt_lds[t + 256] = 0u;
    if (t == 0) red_tot = 0.f;

    const int pix0 = blockIdx.x << 8;
    const int b    = pix0 >> 12;
    const int hwb  = pix0 & (HWSZ - 1);

    // Stage x (thread t = pixel t): coalesced global reads, b128 LDS writes.
    const float* inb = in + b * (DDIM * HWSZ) + hwb + t;
    float x2 = 0.f;
#pragma unroll
    for (int c = 0; c < DDIM; c += 4) {
        float4 v;
        v.x = inb[(c + 0) * HWSZ]; v.y = inb[(c + 1) * HWSZ];
        v.z = inb[(c + 2) * HWSZ]; v.w = inb[(c + 3) * HWSZ];
        *reinterpret_cast<float4*>(&xs[t * 68 + c]) = v;
        x2 = fmaf(v.x, v.x, x2); x2 = fmaf(v.y, v.y, x2);
        x2 = fmaf(v.z, v.z, x2); x2 = fmaf(v.w, v.w, x2);
    }
    x2_lds[t] = x2;
    nrm_lds[t]       = ws[WS_NRM_OFF + t];
    nrm_lds[t + 256] = ws[WS_NRM_OFF + t + 256];
    __syncthreads();

    const int l = t & 63, wid = t >> 6;   // wave handles pixels [wid*64, +64)

    // A-fragments (A[m][k]: m=lane&15, k=(lane>>4)*8+j), hi/lo bf16 split.
    bf16x8 a_hi[4][2], a_lo[4][2];
#pragma unroll
    for (int pt = 0; pt < 4; ++pt)
#pragma unroll
    for (int ks = 0; ks < 2; ++ks) {
        int pixl = wid * 64 + pt * 16 + (l & 15);
        int d0   = ks * 32 + ((l >> 4) & 3) * 8;
        const float4* p = reinterpret_cast<const float4*>(&xs[pixl * 68 + d0]);
        float4 f0 = p[0], f1 = p[1];
        float fv[8] = {f0.x, f0.y, f0.z, f0.w, f1.x, f1.y, f1.z, f1.w};
        bf16x8 h8, l8;
#pragma unroll
        for (int j = 0; j < 8; ++j) {
            __bf16 hb = (__bf16)fv[j];
            h8[j] = hb;
            l8[j] = (__bf16)(fv[j] - (float)hb);
        }
        a_hi[pt][ks] = h8; a_lo[pt][ks] = l8;
    }

    const uint4* fragp = reinterpret_cast<const uint4*>(ws + WS_FRAG_F32);
    float best[4][4]; int bidx[4][4];
#pragma unroll
    for (int pt = 0; pt < 4; ++pt)
#pragma unroll
    for (int r = 0; r < 4; ++r) { best[pt][r] = 3.4e38f; bidx[pt][r] = 0; }

    // B-frag double buffer: 8 frags/chunk = [ct][ks][h]
    uint4 bcur[8], bnxt[8];
#pragma unroll
    for (int i = 0; i < 8; ++i) {
        int ct = i >> 2, ks = (i >> 1) & 1, h = i & 1;
        bcur[i] = fragp[(((ct) * 2 + ks) * 2 + h) * 64 + l];
    }

    for (int cb = 0; cb < KCODES; cb += 32) {
        int ctb = cb >> 4;
        if (cb + 32 < KCODES) {
#pragma unroll
            for (int i = 0; i < 8; ++i) {
                int ct = i >> 2, ks = (i >> 1) & 1, h = i & 1;
                bnxt[i] = fragp[(((ctb + 2 + ct) * 2 + ks) * 2 + h) * 64 + l];
            }
        }
        // 64 pix x 32 codes: 8 C-tiles, 4-term bf16 split accumulated in fp32
        f32x4 acc[4][2];
#pragma unroll
        for (int pt = 0; pt < 4; ++pt)
#pragma unroll
        for (int ct = 0; ct < 2; ++ct) {
            f32x4 a = {0.f, 0.f, 0.f, 0.f};
#pragma unroll
            for (int ks = 0; ks < 2; ++ks) {
                bf16x8 bh = __builtin_bit_cast(bf16x8, bcur[ct * 4 + ks * 2 + 0]);
                bf16x8 bl = __builtin_bit_cast(bf16x8, bcur[ct * 4 + ks * 2 + 1]);
                a = __builtin_amdgcn_mfma_f32_16x16x32_bf16(a_hi[pt][ks], bh, a, 0, 0, 0);
                a = __builtin_amdgcn_mfma_f32_16x16x32_bf16(a_hi[pt][ks], bl, a, 0, 0, 0);
                a = __builtin_amdgcn_mfma_f32_16x16x32_bf16(a_lo[pt][ks], bh, a, 0, 0, 0);
                a = __builtin_amdgcn_mfma_f32_16x16x32_bf16(a_lo[pt][ks], bl, a, 0, 0, 0);
            }
            acc[pt][ct] = a;
        }
        // argmin update; C/D: col(code)=lane&15, row(pix)=(lane>>4)*4+reg
#pragma unroll
        for (int ct = 0; ct < 2; ++ct) {
            int code = cb + ct * 16 + (l & 15);
            float nv = nrm_lds[code];
#pragma unroll
            for (int pt = 0; pt < 4; ++pt)
#pragma unroll
            for (int r = 0; r < 4; ++r) {
                float d = fmaf(-2.f, acc[pt][ct][r], nv);
                if (d < best[pt][r]) { best[pt][r] = d; bidx[pt][r] = code; }
            }
        }
#pragma unroll
        for (int i = 0; i < 8; ++i) bcur[i] = bnxt[i];
    }

    // Cross-lane argmin within each 16-lane group (codes spread over lane&15);
    // (dist, then idx) min = exact first-min semantics.
#pragma unroll
    for (int off = 1; off < 16; off <<= 1) {
#pragma unroll
        for (int pt = 0; pt < 4; ++pt)
#pragma unroll
        for (int r = 0; r < 4; ++r) {
            float ob = __shfl_xor(best[pt][r], off, 64);
            int   oi = __shfl_xor(bidx[pt][r], off, 64);
            bool take = (ob < best[pt][r]) || (ob == best[pt][r] && oi < bidx[pt][r]);
            if (take) { best[pt][r] = ob; bidx[pt][r] = oi; }
        }
    }
    if ((l & 15) == 0) {
        int q = l >> 4;
        float lp = 0.f;
#pragma unroll
        for (int pt = 0; pt < 4; ++pt)
#pragma unroll
        for (int r = 0; r < 4; ++r) {
            int pixl = wid * 64 + pt * 16 + q * 4 + r;
            idx_lds[pixl] = bidx[pt][r];
            atomicAdd(&cnt_lds[bidx[pt][r]], 1u);
            lp += x2_lds[pixl] + best[pt][r];   // |x-e|^2 = x^2 + (|e|^2 - 2x.e)
        }
        atomicAdd(&red_tot, lp);
    }
    __syncthreads();

    if (t == 0) atomicAdd(ws, red_tot);
    unsigned* gcnt = reinterpret_cast<unsigned*>(ws) + WS_CNT_OFF;
    atomicAdd(gcnt + t, cnt_lds[t]);
    atomicAdd(gcnt + t + 256, cnt_lds[t + 256]);

    // Epilogue (R0-proven, token-identical): padded LDS tile (aliases xs)
    // makes both NHWC and NCHW writes coalesced and LDS-conflict-free.
    float* q_lds = xs;                  // [64][65]
    float* out2 = out + OUT_NCHW_OFF;   // NCHW
    float* out3 = out + OUT_NHWC_OFF;   // NHWC flat (float2-aligned)
    const float2* emb2 = reinterpret_cast<const float2*>(emb);
    float2* out3_2 = reinterpret_cast<float2*>(out3);

    for (int s = 0; s < 4; ++s) {
#pragma unroll
        for (int it = 0; it < 8; ++it) {
            int fid = it * 256 + t;
            int pp  = fid >> 5;
            int c2  = fid & 31;
            int row = idx_lds[s * 64 + pp];
            float2 v = emb2[row * 32 + c2];
            out3_2[(size_t)(pix0 + s * 64 + pp) * 32 + c2] = v;
            q_lds[pp * 65 + c2 * 2 + 0] = v.x;
            q_lds[pp * 65 + c2 * 2 + 1] = v.y;
        }
        __syncthreads();
#pragma unroll
        for (int it = 0; it < 16; ++it) {
            int did = it * 256 + t;
            int c   = did >> 6;
            int hwl = did & 63;
            out2[(size_t)(b * DDIM + c) * HWSZ + hwb + s * 64 + hwl] = q_lds[hwl * 65 + c];
        }
        __syncthreads();
    }
}

__global__ __launch_bounds__(256) void vq_fin(float* __restrict__ out,
                                              const float* __restrict__ ws) {
    const unsigned* cnt = reinterpret_cast<const unsigned*>(ws) + WS_CNT_OFF;
    int t = threadIdx.x;  // 256
    double s = 0.0;
#pragma unroll
    for (int k = t; k < KCODES; k += 256) {
        double p = (double)cnt[k] / (double)NPIX;
        s += p * log(p + 1e-10);
    }
#pragma unroll
    for (int o = 32; o > 0; o >>= 1) s += __shfl_xor(s, o, 64);
    __shared__ double rd[4];
    if ((t & 63) == 0) rd[t >> 6] = s;
    __syncthreads();
    if (t == 0) {
        double tot = rd[0] + rd[1] + rd[2] + rd[3];
        out[OUT_PERP_IDX] = (float)exp(-tot);
        out[0] = 0.25f * ws[0] / (float)NELEM;
    }
}

extern "C" void kernel_launch(void* const* d_in, const int* in_sizes, int n_in,
                              void* d_out, int out_size, void* d_ws, size_t ws_size,
                              hipStream_t stream) {
    const float* in  = (const float*)d_in[0];
    const float* emb = (const float*)d_in[1];
    float* out = (float*)d_out;
    float* ws  = (float*)d_ws;

    // vq_prep zeroes loss+counts and overwrites norms + frag region:
    // no memset dispatch needed. Kernel boundaries provide the ordering that
    // the (regression-proven) in-kernel ticket tried to provide.
    vq_prep<<<32, 256, 0, stream>>>(emb, ws);
    vq_main<<<NPIX / 256, 256, 0, stream>>>(in, emb, out, ws);
    vq_fin<<<1, 256, 0, stream>>>(out, ws);
}

// Round 9
// 129.904 us; speedup vs baseline: 1.1978x; 1.0108x over previous
//
#include <hip/hip_runtime.h>
#include <math.h>

// Problem constants
#define NPIX   131072      // 32 * 64 * 64 pixels
#define KCODES 512
#define DDIM   64
#define HWSZ   4096        // 64*64
#define NELEM  8388608     // NPIX * DDIM

// d_out layout (fp32): [0]=loss, [1..1+NELEM)=q_nchw, [1+NELEM]=perplexity,
// [2+NELEM .. 2+2*NELEM)=q_nhwc flat
#define OUT_NCHW_OFF 1
#define OUT_PERP_IDX (1 + NELEM)
#define OUT_NHWC_OFF (2 + NELEM)

// ws layout (fp32 words): [0]=loss, [16..528)=|e|^2, [544..1056)=counts(uint),
// [2048..) = e bf16 hi/lo fragments in MFMA B-layout (byte 8192, 128KB)
#define WS_NRM_OFF  16
#define WS_CNT_OFF  544
#define WS_FRAG_F32 2048

typedef __bf16 bf16x8 __attribute__((ext_vector_type(8)));
typedef float  f32x4  __attribute__((ext_vector_type(4)));

// Fused prep (memset + norms + pack in one dispatch; proven R2-R8). Thread
// tid = [ctile(32)][kstep(2)][h(2)][lane(64)] packs e into bf16 hi/lo MFMA
// B-fragments (16x16x32: B[k][n], n=lane&15, k=(lane>>4)*8+j); 16B coalesced.
// tid<512 computes |e|^2; tid in [512,1024) zeros counts; tid 0 zeros loss.
__global__ __launch_bounds__(256) void vq_prep(const float* __restrict__ emb,
                                               float* __restrict__ ws) {
    int tid  = blockIdx.x * 256 + threadIdx.x;   // 0..8191
    if (tid == 0) ws[0] = 0.f;
    if (tid < KCODES) {
        const float4* e4 = reinterpret_cast<const float4*>(emb + tid * DDIM);
        float s = 0.f;
#pragma unroll
        for (int i = 0; i < 16; ++i) {
            float4 v = e4[i];
            s = fmaf(v.x, v.x, s); s = fmaf(v.y, v.y, s);
            s = fmaf(v.z, v.z, s); s = fmaf(v.w, v.w, s);
        }
        ws[WS_NRM_OFF + tid] = s;
    } else if (tid < 2 * KCODES) {
        reinterpret_cast<unsigned*>(ws)[WS_CNT_OFF + (tid - KCODES)] = 0u;
    }

    int lane = tid & 63;
    int h    = (tid >> 6) & 1;
    int ks   = (tid >> 7) & 1;
    int ct   = tid >> 8;                         // 0..31
    int code = ct * 16 + (lane & 15);
    int d0   = ks * 32 + ((lane >> 4) & 3) * 8;
    const float* src = emb + code * DDIM + d0;
    unsigned short us[8];
#pragma unroll
    for (int j = 0; j < 8; ++j) {
        float f = src[j];
        __bf16 hb = (__bf16)f;                       // RTN
        if (h == 0) {
            us[j] = __builtin_bit_cast(unsigned short, hb);
        } else {
            __bf16 lb = (__bf16)(f - (float)hb);
            us[j] = __builtin_bit_cast(unsigned short, lb);
        }
    }
    uint4 v;
    v.x = us[0] | ((unsigned)us[1] << 16);
    v.y = us[2] | ((unsigned)us[3] << 16);
    v.z = us[4] | ((unsigned)us[5] << 16);
    v.w = us[6] | ((unsigned)us[7] << 16);
    reinterpret_cast<uint4*>(ws + WS_FRAG_F32)[tid] = v;
}

// One code-chunk (32 codes): optional prefetch of next chunk's B-frags into
// BNXT, then 64 MFMA (4-term bf16 hi/lo split, setprio(1) around the MFMA
// cluster — T5: free-running waves regime), then argmin update. Inlined with
// named arrays at both call sites -> all indexing static (no scratch).
// Operation sequence per wave is token-identical to R8's loop body.
__device__ __forceinline__ void vq_chunk(
    int cc, bool dopf, const uint4* __restrict__ fragp, int l,
    uint4 (&bcur)[8], uint4 (&bnxt)[8],
    const bf16x8 (&a_hi)[4][2], const bf16x8 (&a_lo)[4][2],
    const float* __restrict__ nrm_lds,
    float (&best)[4][4], int (&bidx)[4][4]) {
    if (dopf) {
        const int ctb = (cc + 1) << 1;
#pragma unroll
        for (int i = 0; i < 8; ++i) {
            int ct = i >> 2, ks = (i >> 1) & 1, h = i & 1;
            bnxt[i] = fragp[(((ctb + ct) * 2 + ks) * 2 + h) * 64 + l];
        }
    }
    // 64 pix x 32 codes: 8 C-tiles, 4-term bf16 split accumulated in fp32
    f32x4 acc[4][2];
    __builtin_amdgcn_s_setprio(1);
#pragma unroll
    for (int pt = 0; pt < 4; ++pt)
#pragma unroll
    for (int ct = 0; ct < 2; ++ct) {
        f32x4 a = {0.f, 0.f, 0.f, 0.f};
#pragma unroll
        for (int ks = 0; ks < 2; ++ks) {
            bf16x8 bh = __builtin_bit_cast(bf16x8, bcur[ct * 4 + ks * 2 + 0]);
            bf16x8 bl = __builtin_bit_cast(bf16x8, bcur[ct * 4 + ks * 2 + 1]);
            a = __builtin_amdgcn_mfma_f32_16x16x32_bf16(a_hi[pt][ks], bh, a, 0, 0, 0);
            a = __builtin_amdgcn_mfma_f32_16x16x32_bf16(a_hi[pt][ks], bl, a, 0, 0, 0);
            a = __builtin_amdgcn_mfma_f32_16x16x32_bf16(a_lo[pt][ks], bh, a, 0, 0, 0);
            a = __builtin_amdgcn_mfma_f32_16x16x32_bf16(a_lo[pt][ks], bl, a, 0, 0, 0);
        }
        acc[pt][ct] = a;
    }
    __builtin_amdgcn_s_setprio(0);
    // argmin update; C/D: col(code)=lane&15, row(pix)=(lane>>4)*4+reg
    const int cb = cc << 5;
#pragma unroll
    for (int ct = 0; ct < 2; ++ct) {
        int code = cb + ct * 16 + (l & 15);
        float nv = nrm_lds[code];
#pragma unroll
        for (int pt = 0; pt < 4; ++pt)
#pragma unroll
        for (int r = 0; r < 4; ++r) {
            float d = fmaf(-2.f, acc[pt][ct][r], nv);
            if (d < best[pt][r]) { best[pt][r] = d; bidx[pt][r] = code; }
        }
    }
}

// Main — R8's reproduced-proven 56us kernel; only changes are inside the
// chunk loop (bit-exact scheduling tweaks): (1) ping-pong 2-chunk unroll
// (b0/b1 named buffers — removes 8 uint4 copies/chunk, lets the compiler
// software-pipeline B-loads across chunks), (2) s_setprio(1) around each
// chunk's MFMA cluster (waves free-run here — the regime where setprio pays).
// FP operation sequence per wave unchanged -> identical argmin -> identical
// outputs. Tail = R0 ordering (relaxed atomics before epilogue, no ticket —
// R6/R7 proved ordered agent-scope atomics cost 15-30us of stall).
__global__ __launch_bounds__(256, 2) void vq_main(const float* __restrict__ in,
                                                  const float* __restrict__ emb,
                                                  float* __restrict__ out,
                                                  float* __restrict__ ws) {
    __shared__ __align__(16) float xs[256 * 68];  // x [pix][d] pad-68; reused as q tile
    __shared__ float    x2_lds[256];
    __shared__ float    nrm_lds[KCODES];
    __shared__ int      idx_lds[256];
    __shared__ unsigned cnt_lds[KCODES];
    __shared__ float    red_tot;

    const int t = threadIdx.x;
    cnt_lds[t] = 0u; cnt_lds[t + 256] = 0u;
    if (t == 0) red_tot = 0.f;

    const int pix0 = blockIdx.x << 8;
    const int b    = pix0 >> 12;
    const int hwb  = pix0 & (HWSZ - 1);

    // Stage x (thread t = pixel t): coalesced global reads, b128 LDS writes.
    const float* inb = in + b * (DDIM * HWSZ) + hwb + t;
    float x2 = 0.f;
#pragma unroll
    for (int c = 0; c < DDIM; c += 4) {
        float4 v;
        v.x = inb[(c + 0) * HWSZ]; v.y = inb[(c + 1) * HWSZ];
        v.z = inb[(c + 2) * HWSZ]; v.w = inb[(c + 3) * HWSZ];
        *reinterpret_cast<float4*>(&xs[t * 68 + c]) = v;
        x2 = fmaf(v.x, v.x, x2); x2 = fmaf(v.y, v.y, x2);
        x2 = fmaf(v.z, v.z, x2); x2 = fmaf(v.w, v.w, x2);
    }
    x2_lds[t] = x2;
    nrm_lds[t]       = ws[WS_NRM_OFF + t];
    nrm_lds[t + 256] = ws[WS_NRM_OFF + t + 256];
    __syncthreads();

    const int l = t & 63, wid = t >> 6;   // wave handles pixels [wid*64, +64)

    // A-fragments (A[m][k]: m=lane&15, k=(lane>>4)*8+j), hi/lo bf16 split.
    bf16x8 a_hi[4][2], a_lo[4][2];
#pragma unroll
    for (int pt = 0; pt < 4; ++pt)
#pragma unroll
    for (int ks = 0; ks < 2; ++ks) {
        int pixl = wid * 64 + pt * 16 + (l & 15);
        int d0   = ks * 32 + ((l >> 4) & 3) * 8;
        const float4* p = reinterpret_cast<const float4*>(&xs[pixl * 68 + d0]);
        float4 f0 = p[0], f1 = p[1];
        float fv[8] = {f0.x, f0.y, f0.z, f0.w, f1.x, f1.y, f1.z, f1.w};
        bf16x8 h8, l8;
#pragma unroll
        for (int j = 0; j < 8; ++j) {
            __bf16 hb = (__bf16)fv[j];
            h8[j] = hb;
            l8[j] = (__bf16)(fv[j] - (float)hb);
        }
        a_hi[pt][ks] = h8; a_lo[pt][ks] = l8;
    }

    const uint4* fragp = reinterpret_cast<const uint4*>(ws + WS_FRAG_F32);
    float best[4][4]; int bidx[4][4];
#pragma unroll
    for (int pt = 0; pt < 4; ++pt)
#pragma unroll
    for (int r = 0; r < 4; ++r) { best[pt][r] = 3.4e38f; bidx[pt][r] = 0; }

    // B-frag ping-pong: b0/b1 alternate as cur/next each chunk; 8 frags/chunk
    // = [ct][ks][h]. Barrier-free: waves free-run, prefetch covers L2 latency.
    uint4 b0[8], b1[8];
#pragma unroll
    for (int i = 0; i < 8; ++i) {
        int ct = i >> 2, ks = (i >> 1) & 1, h = i & 1;
        b0[i] = fragp[(((ct) * 2 + ks) * 2 + h) * 64 + l];
    }

#pragma unroll 1
    for (int c = 0; c < 16; c += 2) {
        vq_chunk(c,     true,           fragp, l, b0, b1, a_hi, a_lo, nrm_lds, best, bidx);
        vq_chunk(c + 1, (c + 1) < 15,   fragp, l, b1, b0, a_hi, a_lo, nrm_lds, best, bidx);
    }

    // Cross-lane argmin within each 16-lane group (codes spread over lane&15);
    // (dist, then idx) min = exact first-min semantics.
#pragma unroll
    for (int off = 1; off < 16; off <<= 1) {
#pragma unroll
        for (int pt = 0; pt < 4; ++pt)
#pragma unroll
        for (int r = 0; r < 4; ++r) {
            float ob = __shfl_xor(best[pt][r], off, 64);
            int   oi = __shfl_xor(bidx[pt][r], off, 64);
            bool take = (ob < best[pt][r]) || (ob == best[pt][r] && oi < bidx[pt][r]);
            if (take) { best[pt][r] = ob; bidx[pt][r] = oi; }
        }
    }
    if ((l & 15) == 0) {
        int q = l >> 4;
        float lp = 0.f;
#pragma unroll
        for (int pt = 0; pt < 4; ++pt)
#pragma unroll
        for (int r = 0; r < 4; ++r) {
            int pixl = wid * 64 + pt * 16 + q * 4 + r;
            idx_lds[pixl] = bidx[pt][r];
            atomicAdd(&cnt_lds[bidx[pt][r]], 1u);
            lp += x2_lds[pixl] + best[pt][r];   // |x-e|^2 = x^2 + (|e|^2 - 2x.e)
        }
        atomicAdd(&red_tot, lp);
    }
    __syncthreads();

    // Relaxed global atomics issued before the epilogue (R0 ordering): they
    // drain at the first epilogue barrier, overlapped with the gather phase.
    if (t == 0) atomicAdd(ws, red_tot);
    unsigned* gcnt = reinterpret_cast<unsigned*>(ws) + WS_CNT_OFF;
    atomicAdd(gcnt + t, cnt_lds[t]);
    atomicAdd(gcnt + t + 256, cnt_lds[t + 256]);

    // Epilogue (R0-proven, token-identical): padded LDS tile (aliases xs)
    // makes both NHWC and NCHW writes coalesced and LDS-conflict-free.
    float* q_lds = xs;                  // [64][65]
    float* out2 = out + OUT_NCHW_OFF;   // NCHW
    float* out3 = out + OUT_NHWC_OFF;   // NHWC flat (float2-aligned)
    const float2* emb2 = reinterpret_cast<const float2*>(emb);
    float2* out3_2 = reinterpret_cast<float2*>(out3);

    for (int s = 0; s < 4; ++s) {
#pragma unroll
        for (int it = 0; it < 8; ++it) {
            int fid = it * 256 + t;
            int pp  = fid >> 5;
            int c2  = fid & 31;
            int row = idx_lds[s * 64 + pp];
            float2 v = emb2[row * 32 + c2];
            out3_2[(size_t)(pix0 + s * 64 + pp) * 32 + c2] = v;
            q_lds[pp * 65 + c2 * 2 + 0] = v.x;
            q_lds[pp * 65 + c2 * 2 + 1] = v.y;
        }
        __syncthreads();
#pragma unroll
        for (int it = 0; it < 16; ++it) {
            int did = it * 256 + t;
            int c   = did >> 6;
            int hwl = did & 63;
            out2[(size_t)(b * DDIM + c) * HWSZ + hwb + s * 64 + hwl] = q_lds[hwl * 65 + c];
        }
        __syncthreads();
    }
}

__global__ __launch_bounds__(256) void vq_fin(float* __restrict__ out,
                                              const float* __restrict__ ws) {
    const unsigned* cnt = reinterpret_cast<const unsigned*>(ws) + WS_CNT_OFF;
    int t = threadIdx.x;  // 256
    double s = 0.0;
#pragma unroll
    for (int k = t; k < KCODES; k += 256) {
        double p = (double)cnt[k] / (double)NPIX;
        s += p * log(p + 1e-10);
    }
#pragma unroll
    for (int o = 32; o > 0; o >>= 1) s += __shfl_xor(s, o, 64);
    __shared__ double rd[4];
    if ((t & 63) == 0) rd[t >> 6] = s;
    __syncthreads();
    if (t == 0) {
        double tot = rd[0] + rd[1] + rd[2] + rd[3];
        out[OUT_PERP_IDX] = (float)exp(-tot);
        out[0] = 0.25f * ws[0] / (float)NELEM;
    }
}

extern "C" void kernel_launch(void* const* d_in, const int* in_sizes, int n_in,
                              void* d_out, int out_size, void* d_ws, size_t ws_size,
                              hipStream_t stream) {
    const float* in  = (const float*)d_in[0];
    const float* emb = (const float*)d_in[1];
    float* out = (float*)d_out;
    float* ws  = (float*)d_ws;

    // vq_prep zeroes loss+counts and overwrites norms + frag region:
    // no memset dispatch needed. Kernel boundaries provide cross-block
    // ordering (in-kernel tickets proven to cost 15-30us, R6/R7).
    vq_prep<<<32, 256, 0, stream>>>(emb, ws);
    vq_main<<<NPIX / 256, 256, 0, stream>>>(in, emb, out, ws);
    vq_fin<<<1, 256, 0, stream>>>(out, ws);
}